// Round 6
// baseline (334.308 us; speedup 1.0000x reference)
//
#include <hip/hip_runtime.h>

#define T_STEPS 256
#define HID 40
#define EPB 16
#define NTHR 128               // 2 waves: wave0 = L0, wave1 = L1
#define RRH 56                 // row stride (shorts) within a slot: [h(40) | pad(16)]; 2-way banks only
#define SLOT (16 * RRH)        // 896 shorts per ring slot (16 cols)
#define NSLOT 16               // h0 ring depth
#define H1B (NSLOT * SLOT)     // h1 region offset = 14336 shorts
#define STOT (H1B + SLOT)      // 15232 shorts = 30464 B

typedef __attribute__((ext_vector_type(8))) short bf16x8;
typedef __attribute__((ext_vector_type(4))) float f32x4;
typedef __attribute__((ext_vector_type(8))) float f32x8;
typedef __attribute__((ext_vector_type(4))) unsigned int u32x4;

__device__ __forceinline__ unsigned short bf16_rne(float v) {
    unsigned int x = __float_as_uint(v);
    unsigned int r = x + 0x7FFFu + ((x >> 16) & 1u);
    return (unsigned short)(r >> 16);
}
__device__ __forceinline__ unsigned short bf16_cvt(float v) {
    unsigned int r;
    asm("v_cvt_pk_bf16_f32 %0, %1, %2" : "=v"(r) : "v"(v), "v"(v));
    return (unsigned short)r;
}
// fast gates (r16-proven): v_exp_f32 = 2^x; v_rcp_f32 replaces IEEE divide
__device__ __forceinline__ float sigm(float v) {
    return __builtin_amdgcn_rcpf(1.0f + __builtin_amdgcn_exp2f(-1.4426950408889634f * v));
}
__device__ __forceinline__ float tanh_f(float v) {
    return 1.0f - 2.0f * __builtin_amdgcn_rcpf(__builtin_amdgcn_exp2f(2.8853900817779268f * v) + 1.0f);
}

#define MF(A_, B_, C_) C_ = __builtin_amdgcn_mfma_f32_16x16x32_bf16(A_, B_, C_, 0, 0, 0)
#define PINV(v) asm volatile("" : "+v"(v))

// A-frag over unified K-concat rows [h_self(40) | input(KX)] (r15-proven mapping).
// element at k = 32c + 8qrow + j: k<40 -> Whh[rh][k]; 40<=k<40+KX -> Wih[rx][k-40]; else 0.
// For L0 (KX=16), chunk c=2 is all-zero automatically.
__device__ bf16x8 afrag(const float* Whh, const float* Wih, int KX,
                        int rh, int rx, int c, int qrow) {
    bf16x8 f;
    #pragma unroll
    for (int j = 0; j < 8; ++j) f[j] = 0;
    #pragma unroll
    for (int j = 0; j < 8; ++j) {
        const int k = 32 * c + qrow * 8 + j;
        if (k < 40) {
            if (rh >= 0) f[j] = (short)bf16_rne(Whh[rh * 40 + k]);
        } else if (k < 40 + KX) {
            if (rx >= 0) f[j] = (short)bf16_rne(Wih[rx * KX + (k - 40)]);
        }
    }
    return f;
}

// r20 (resubmit after infra failure): BARRIER-ELIMINATION via wave-owned
// layers. Evidence from r1/r2/r4: step time ~1400-1600cy regardless of wave
// count / LDS traffic -> fixed ~500-800cy cost PER BARRIER INTERVAL
// dominates. Fix: wave0 owns ALL of L0 (10 tiles; B-reads shared across
// tiles -> 2 ds_read_b128/step), wave1 owns ALL of L1 (3 reads/step).
// Self-recurrence h->h within a wave needs NO barrier (in-order DS pipe
// orders same-wave write->read). Cross-layer h0 flows through a 16-slot LDS
// ring; L1 lags 4 steps; ONE __syncthreads per 4-step superstep (65 barriers
// total vs 257).
//   superstep b: L0 does t = 4b..4b+3  (writes ring slots t&15)
//               L1 does tau = 4(b-1)..4(b-1)+3 (reads h0[tau] = slot tau&15)
// Disjointness: write slots {4b..4b+3} vs read slots {4b-4..4b-1}: diffs 1..7
// mod 16 != 0. Slot overwritten 3 barriers after its last read. h1 is
// single-buffered (same-wave read-then-write per step). x: global->reg
// 2-deep ring (parity j&1 compile-time in the 4-step unroll), cvt_pk-spliced
// into L0's chunk-1 B-frag lanes (qrow 1,2).
__global__ __launch_bounds__(NTHR, 1)
void gru2_kernel(const float* __restrict__ x,
                 const float* __restrict__ Wih0, const float* __restrict__ Whh0,
                 const float* __restrict__ bih0, const float* __restrict__ bhh0,
                 const float* __restrict__ Wih1, const float* __restrict__ Whh1,
                 const float* __restrict__ bih1, const float* __restrict__ bhh1,
                 float* __restrict__ out)
{
    __shared__ __align__(16) unsigned short S[STOT];

    const int tid  = threadIdx.x;
    const int wid  = tid >> 6;     // 0 = L0, 1 = L1
    const int l    = tid & 63;
    const int col  = l & 15;       // example / MFMA col / A-frag row pm
    const int qrow = l >> 4;
    const int ps   = col & 3;      // slot (0=r,1=z,2=nx,3=nh)
    const int pu   = col >> 2;     // unit-in-tile
    const int e0   = blockIdx.x * EPB;
    const bool isL1 = (wid == 1);

    const float* Whh = isL1 ? Whh1 : Whh0;
    const float* Wih = isL1 ? Wih1 : Wih0;
    const float* bih = isL1 ? bih1 : bih0;
    const float* bhh = isL1 ? bhh1 : bhh0;
    const int KX = isL1 ? 40 : 16;

    // ---- weight A-frags: 10 tiles x 3 chunks (L0 chunk2 = zeros), biases, state ----
    bf16x8 F[10][3];
    f32x4  BB[10];
    float  H[10];
    #pragma unroll
    for (int m = 0; m < 10; ++m) {
        const int u  = 4 * m + pu;
        const int rh = (ps == 2) ? -1 : (ps == 0 ? u : ps == 1 ? 40 + u : 80 + u);
        const int rx = (ps == 3) ? -1 : (ps == 0 ? u : ps == 1 ? 40 + u : 80 + u);
        F[m][0] = afrag(Whh, Wih, KX, rh, rx, 0, qrow);
        F[m][1] = afrag(Whh, Wih, KX, rh, rx, 1, qrow);
        F[m][2] = afrag(Whh, Wih, KX, rh, rx, 2, qrow);
        const int uc = 4 * m + qrow;
        BB[m][0] = bih[uc] + bhh[uc];
        BB[m][1] = bih[40 + uc] + bhh[40 + uc];
        BB[m][2] = bih[80 + uc];
        BB[m][3] = bhh[80 + uc];
        H[m] = 0.f;
    }
    #pragma unroll
    for (int m = 0; m < 10; ++m) {
        PINV(F[m][0]); PINV(F[m][1]); PINV(F[m][2]); PINV(BB[m]);
    }

    // ---- per-lane LDS offsets (shorts) ----
    // L0 reads ring slot (t-1): S0 = h0[8q..], S1 = h0[32..39] (qrow0; others spliced/dead)
    const int rdl0 = col * RRH + 8 * qrow;
    const int rdl1 = col * RRH + 32;
    const int w0l  = col * RRH + qrow;            // + slot, + 4m imm
    // L1: S0 = h1[8q..] (static, single-buffer); S1: qrow0 -> h1[32..39] (static),
    // qrow1..3 -> h0[8(qrow-1)..] (ring); S2: qrow0 -> h0[24..31], qrow1 -> h0[32..39],
    // qrow2/3 dead (A=0, any finite addr).
    const int rdh1 = H1B + col * RRH + 8 * qrow;
    const int off1 = (qrow == 0) ? (H1B + col * RRH + 32) : (col * RRH + 8 * (qrow - 1));
    const int msk1 = (qrow == 0) ? 0 : -1;
    const int off2 = (qrow == 0) ? (col * RRH + 24)
                   : (qrow == 1) ? (col * RRH + 32) : (col * RRH);
    const int w1l  = H1B + col * RRH + qrow;
    const bool usex = (qrow == 1) || (qrow == 2);
    unsigned short* Sb = &S[0];

    // ---- zero ALL LDS (h(-1)=0; garbage could be Inf/NaN -> 0*Inf = NaN in MFMA) ----
    for (int i = tid; i < STOT; i += NTHR) Sb[i] = 0;

    // ---- x: 2-deep register ring (L0 wave only) ----
    const float* xrow = x + (size_t)(e0 + col) * (T_STEPS * 16) + ((qrow == 2) ? 8 : 0);
    f32x8 XRa, XRb;
    #pragma unroll
    for (int j = 0; j < 8; ++j) { XRa[j] = 0.f; XRb[j] = 0.f; }
    if (!isL1) {
        XRa = *(const f32x8*)(xrow);          // x[0]
        XRb = *(const f32x8*)(xrow + 16);     // x[1]
    }
    __syncthreads();

#define GMATH(C, Hm) \
    const float r_ = sigm(C[0]); \
    const float z_ = sigm(C[1]); \
    const float n_ = tanh_f(C[2] + r_ * C[3]); \
    Hm = n_ + z_ * (Hm - n_);

#define L0STEP(J, XREG) { \
    const int t   = 4 * b + (J); \
    const int rsr = ((t - 1) & 15) * SLOT; \
    const int wsr = (t & 15) * SLOT; \
    const bf16x8 S0 = *(const bf16x8*)(Sb + rsr + rdl0); \
    bf16x8 S1 = *(const bf16x8*)(Sb + rsr + rdl1); \
    unsigned int xw0, xw1, xw2, xw3; \
    asm("v_cvt_pk_bf16_f32 %0, %1, %2" : "=v"(xw0) : "v"(XREG[0]), "v"(XREG[1])); \
    asm("v_cvt_pk_bf16_f32 %0, %1, %2" : "=v"(xw1) : "v"(XREG[2]), "v"(XREG[3])); \
    asm("v_cvt_pk_bf16_f32 %0, %1, %2" : "=v"(xw2) : "v"(XREG[4]), "v"(XREG[5])); \
    asm("v_cvt_pk_bf16_f32 %0, %1, %2" : "=v"(xw3) : "v"(XREG[6]), "v"(XREG[7])); \
    if (t + 2 < T_STEPS) XREG = *(const f32x8*)(xrow + (t + 2) * 16); \
    u32x4 s1u = *(const u32x4*)&S1; \
    s1u[0] = usex ? xw0 : s1u[0]; \
    s1u[1] = usex ? xw1 : s1u[1]; \
    s1u[2] = usex ? xw2 : s1u[2]; \
    s1u[3] = usex ? xw3 : s1u[3]; \
    S1 = *(const bf16x8*)&s1u; \
    _Pragma("unroll") \
    for (int m = 0; m < 10; ++m) { \
        f32x4 c = __builtin_amdgcn_mfma_f32_16x16x32_bf16(F[m][0], S0, BB[m], 0, 0, 0); \
        MF(F[m][1], S1, c); \
        GMATH(c, H[m]); \
        Sb[wsr + w0l + 4 * m] = bf16_cvt(H[m]); \
    } \
}

#define L1STEP(J) { \
    const int tt  = 4 * (b - 1) + (J); \
    const int rsr = (tt & 15) * SLOT; \
    const int a1  = off1 + (rsr & msk1); \
    const int a2  = off2 + rsr; \
    const bf16x8 S0 = *(const bf16x8*)(Sb + rdh1); \
    const bf16x8 S1 = *(const bf16x8*)(Sb + a1); \
    const bf16x8 S2 = *(const bf16x8*)(Sb + a2); \
    _Pragma("unroll") \
    for (int m = 0; m < 10; ++m) { \
        f32x4 c = __builtin_amdgcn_mfma_f32_16x16x32_bf16(F[m][0], S0, BB[m], 0, 0, 0); \
        MF(F[m][1], S1, c); \
        MF(F[m][2], S2, c); \
        GMATH(c, H[m]); \
        Sb[w1l + 4 * m] = bf16_cvt(H[m]); \
    } \
}

    #pragma unroll 1
    for (int b = 0; b <= 64; ++b) {
        if (!isL1) {
            if (b < 64) {
                L0STEP(0, XRa)
                L0STEP(1, XRb)
                L0STEP(2, XRa)
                L0STEP(3, XRb)
            }
        } else {
            if (b >= 1) {
                L1STEP(0)
                L1STEP(1)
                L1STEP(2)
                L1STEP(3)
            }
        }
        __syncthreads();
    }

    // ---- h1[255] straight from registers ----
    if (isL1) {
        float* op = out + (size_t)(e0 + col) * HID + qrow;
        #pragma unroll
        for (int m = 0; m < 10; ++m) op[4 * m] = H[m];
    }
}

extern "C" void kernel_launch(void* const* d_in, const int* in_sizes, int n_in,
                              void* d_out, int out_size, void* d_ws, size_t ws_size,
                              hipStream_t stream) {
    const float* x    = (const float*)d_in[0];
    const float* Wih0 = (const float*)d_in[1];
    const float* Whh0 = (const float*)d_in[2];
    const float* bih0 = (const float*)d_in[3];
    const float* bhh0 = (const float*)d_in[4];
    const float* Wih1 = (const float*)d_in[5];
    const float* Whh1 = (const float*)d_in[6];
    const float* bih1 = (const float*)d_in[7];
    const float* bhh1 = (const float*)d_in[8];
    float* out = (float*)d_out;

    dim3 grid(4096 / EPB), block(NTHR);
    hipLaunchKernelGGL(gru2_kernel, grid, block, 0, stream,
                       x, Wih0, Whh0, bih0, bhh0, Wih1, Whh1, bih1, bhh1, out);
}

// Round 8
// 234.858 us; speedup vs baseline: 1.4234x; 1.4234x over previous
//
#include <hip/hip_runtime.h>

#define T_STEPS 256
#define HID 40
#define EPB 16
#define NTHR 1024          // 16 waves: 0-5 L0 (tiles 2,2,2,2,1,1), 6-15 L1 (1 tile)
#define RR 56              // row stride (shorts): [h(40) | pad(16)]
#define PP (16 * RR)       // parity stride = 896 shorts
#define OL1 (2 * PP)       // L1 region offset = 1792 shorts
#define STOT (4 * PP)      // 3584 shorts = 7168 B

typedef __attribute__((ext_vector_type(8))) short bf16x8;
typedef __attribute__((ext_vector_type(4))) float f32x4;
typedef __attribute__((ext_vector_type(8))) float f32x8;
typedef __attribute__((ext_vector_type(4))) unsigned int u32x4;

__device__ __forceinline__ unsigned short bf16_rne(float v) {
    unsigned int x = __float_as_uint(v);
    unsigned int r = x + 0x7FFFu + ((x >> 16) & 1u);
    return (unsigned short)(r >> 16);
}
__device__ __forceinline__ unsigned short bf16_cvt(float v) {
    unsigned int r;
    asm("v_cvt_pk_bf16_f32 %0, %1, %2" : "=v"(r) : "v"(v), "v"(v));
    return (unsigned short)r;
}
// fast gates (r16-proven): v_exp_f32 = 2^x; v_rcp_f32 replaces IEEE divide
__device__ __forceinline__ float sigm(float v) {
    return __builtin_amdgcn_rcpf(1.0f + __builtin_amdgcn_exp2f(-1.4426950408889634f * v));
}
__device__ __forceinline__ float tanh_f(float v) {
    return 1.0f - 2.0f * __builtin_amdgcn_rcpf(__builtin_amdgcn_exp2f(2.8853900817779268f * v) + 1.0f);
}

#define MF(A_, B_, C_) C_ = __builtin_amdgcn_mfma_f32_16x16x32_bf16(A_, B_, C_, 0, 0, 0)
#define PINV(v) asm volatile("" : "+v"(v))

// r22 = r21 with the STEP-COUNT BUG fixed: r21 ran 128 iters x 4 BODYs = 513
// steps (copied R1's count of 128x2+1=257); L1 then iterated 256 extra steps
// against frozen h0 -> absmax 0.2. Correct: 64 iters x 4 + 1 = 257.
//
// RAW BARRIER theory (now actually under test): __syncthreads() = s_waitcnt
// vmcnt(0) lgkmcnt(0) + s_barrier; the vmcnt(0) drains the x prefetch global
// load issued earlier the SAME step -> ~200-900cy exposed per step = the
// fixed per-barrier-interval cost seen across r1/r2/r4 (~1400-1600cy/step,
// invariant to wave count & LDS traffic; r20 refuted barrier COUNT). x loads
// land in REGISTERS (no cross-wave visibility), so lgkmcnt(0) alone
// suffices; loads float across barriers, 4 steps (~5000cy) old at use.
// sched_barrier(0) bracketing per guide rule #18 (hipcc can move insts past
// inline-asm waitcnt despite "memory" clobber).
#define BAR() do { \
    __builtin_amdgcn_sched_barrier(0); \
    asm volatile("s_waitcnt lgkmcnt(0)\n\ts_barrier" ::: "memory"); \
    __builtin_amdgcn_sched_barrier(0); \
} while (0)

// A-frag over unified K-concat rows [h_self(40) | input(KX)] (r15-proven mapping).
__device__ bf16x8 afrag(const float* Whh, const float* Wih, int KX,
                        int rh, int rx, int c, int qrow) {
    bf16x8 f;
    #pragma unroll
    for (int j = 0; j < 8; ++j) f[j] = 0;
    #pragma unroll
    for (int j = 0; j < 8; ++j) {
        const int k = 32 * c + qrow * 8 + j;
        if (k < 40) {
            if (rh >= 0) f[j] = (short)bf16_rne(Whh[rh * 40 + k]);
        } else if (k < 40 + KX) {
            if (rx >= 0) f[j] = (short)bf16_rne(Wih[rx * KX + (k - 40)]);
        }
    }
    return f;
}

// Structure = R1 (proven 147us): 16 waves, 1 barrier/step, layer skew
// (step t: L0 computes h0[t], L1 computes h1[t-1]); ping-pong parity
// (read RP, write 1-RP). Plus r17-proven trims: L1 reads h0 DIRECTLY from
// L0's region (concat [h1|h0] addressing) so L0 writes h0 once; x is
// global->reg 4-deep ring, cvt_pk-spliced into L0's chunk-1 B-frag
// (qrow 1,2 lanes).
__global__ __launch_bounds__(NTHR, 4)
void gru2_kernel(const float* __restrict__ x,
                 const float* __restrict__ Wih0, const float* __restrict__ Whh0,
                 const float* __restrict__ bih0, const float* __restrict__ bhh0,
                 const float* __restrict__ Wih1, const float* __restrict__ Whh1,
                 const float* __restrict__ bih1, const float* __restrict__ bhh1,
                 float* __restrict__ out)
{
    __shared__ __align__(16) unsigned short S[STOT];

    const int tid  = threadIdx.x;
    const int wid  = tid >> 6;     // 0..15
    const int l    = tid & 63;
    const int col  = l & 15;       // example / MFMA col
    const int qrow = l >> 4;
    const int ps   = (l & 15) & 3; // slot (0=r,1=z,2=nx,3=nh)
    const int pu   = (l & 15) >> 2;
    const int e0   = blockIdx.x * EPB;

    const bool isL1 = wid >= 6;
    const int  NT   = (!isL1 && wid < 4) ? 2 : 1;
    const int  TA   = isL1 ? (wid - 6) : (wid < 4 ? 2 * wid : wid + 4);
    const int  TB   = (NT == 2) ? TA + 1 : TA;
    const bool dB   = (NT != 2);

    const float* Whh = isL1 ? Whh1 : Whh0;
    const float* Wih = isL1 ? Wih1 : Wih0;
    const float* bih = isL1 ? bih1 : bih0;
    const float* bhh = isL1 ? bhh1 : bhh0;
    const int KX = isL1 ? 40 : 16;

    // ---- A-frags + biases ----
    bf16x8 ZF;
    #pragma unroll
    for (int j = 0; j < 8; ++j) ZF[j] = 0;
    bf16x8 F00=ZF,F01=ZF,F02=ZF, F10=ZF,F11=ZF;
    f32x4 BB0, BB1;
    {
#define RRX(u, RH, RX) \
        const int RH = (ps == 2) ? -1 : (ps == 0 ? (u) : ps == 1 ? 40 + (u) : 80 + (u)); \
        const int RX = (ps == 3) ? -1 : (ps == 0 ? (u) : ps == 1 ? 40 + (u) : 80 + (u));
        {
            const int u0 = 4 * TA + pu;
            RRX(u0, rh0, rx0);
            F00 = afrag(Whh, Wih, KX, rh0, rx0, 0, qrow);
            F01 = afrag(Whh, Wih, KX, rh0, rx0, 1, qrow);
            if (isL1) F02 = afrag(Whh, Wih, KX, rh0, rx0, 2, qrow);
        }
        if (NT == 2) {
            const int u1 = 4 * TB + pu;
            RRX(u1, rh1, rx1);
            F10 = afrag(Whh, Wih, KX, rh1, rx1, 0, qrow);
            F11 = afrag(Whh, Wih, KX, rh1, rx1, 1, qrow);
        }
        const int uc0 = 4 * TA + qrow;
        const int uc1 = 4 * TB + qrow;
        BB0[0] = bih[uc0] + bhh[uc0];
        BB0[1] = bih[40 + uc0] + bhh[40 + uc0];
        BB0[2] = bih[80 + uc0];
        BB0[3] = bhh[80 + uc0];
        BB1[0] = dB ? 0.f : (bih[uc1] + bhh[uc1]);
        BB1[1] = dB ? 0.f : (bih[40 + uc1] + bhh[40 + uc1]);
        BB1[2] = dB ? 0.f : bih[80 + uc1];
        BB1[3] = dB ? 0.f : bhh[80 + uc1];
    }
    PINV(F00); PINV(F01); PINV(F02);
    PINV(F10); PINV(F11);
    PINV(BB0); PINV(BB1);

    // ---- per-lane LDS addresses (shorts; parity RP*PP added at use) ----
    // L0: chunk0 = h0[8q..8q+7]; chunk1: qrow0 -> h0[32..39], qrow1/2 spliced
    // from x regs, qrow3 dead (A=0, reads h0[32..39] -> finite).
    const int rd0 = col * RR + 8 * qrow;
    const int rd1 = col * RR + 32;
    // L1 concat [h1(40) | h0(40)]: group g = 4c + qrow
    int g0, g1, g2;
    {
        auto ga = [&](int g) -> int {
            if (g < 5)  return OL1 + col * RR + 8 * g;        // h1 (own region)
            if (g < 10) return col * RR + 8 * (g - 5);        // h0 (L0 region)
            return col * RR;                                  // dead lane (A=0)
        };
        g0 = ga(qrow);
        g1 = ga(4 + qrow);
        g2 = ga(8 + qrow);
    }
    // write offsets (parity (1-RP)*PP added at use)
    const int w0  = col * RR + 4 * TA + qrow;         // L0 tile A unit
    const int w0b = col * RR + 4 * TB + qrow;         // L0 tile B unit
    const int w1  = OL1 + col * RR + 4 * TA + qrow;   // L1 unit
    const bool usex = (qrow == 1) || (qrow == 2);
    unsigned short* Sb = &S[0];
    float hA0 = 0.f, hA1 = 0.f;

    // ---- zero LDS (initial h = 0; pads must stay 0) ----
    for (int idx = tid; idx < STOT; idx += NTHR) Sb[idx] = 0;

    // ---- x: 4-deep register ring (L0 waves only) ----
    const float* xrow = x + (size_t)(e0 + col) * (T_STEPS * 16) + ((qrow == 2) ? 8 : 0);
    f32x8 XA, XB, XC, XD;
    #pragma unroll
    for (int j = 0; j < 8; ++j) { XA[j] = 0.f; XB[j] = 0.f; XC[j] = 0.f; XD[j] = 0.f; }
    if (!isL1) {
        XA = *(const f32x8*)(xrow);
        XB = *(const f32x8*)(xrow + 16);
        XC = *(const f32x8*)(xrow + 32);
        XD = *(const f32x8*)(xrow + 48);
    }
    __syncthreads();

#define GMATH(C, H) \
    const float r_ = sigm(C[0]); \
    const float z_ = sigm(C[1]); \
    const float n_ = tanh_f(C[2] + r_ * C[3]); \
    H = n_ + z_ * (H - n_);

#define BODY(RP, XQ) { \
    if (!isL1) { \
        if (t < T_STEPS) { \
            const bf16x8 S0 = *(const bf16x8*)(Sb + rd0 + (RP) * PP); \
            bf16x8 S1 = *(const bf16x8*)(Sb + rd1 + (RP) * PP); \
            unsigned int xw0, xw1, xw2, xw3; \
            asm("v_cvt_pk_bf16_f32 %0, %1, %2" : "=v"(xw0) : "v"(XQ[0]), "v"(XQ[1])); \
            asm("v_cvt_pk_bf16_f32 %0, %1, %2" : "=v"(xw1) : "v"(XQ[2]), "v"(XQ[3])); \
            asm("v_cvt_pk_bf16_f32 %0, %1, %2" : "=v"(xw2) : "v"(XQ[4]), "v"(XQ[5])); \
            asm("v_cvt_pk_bf16_f32 %0, %1, %2" : "=v"(xw3) : "v"(XQ[6]), "v"(XQ[7])); \
            if (t + 4 < T_STEPS) XQ = *(const f32x8*)(xrow + (t + 4) * 16); \
            u32x4 s1u = *(const u32x4*)&S1; \
            s1u[0] = usex ? xw0 : s1u[0]; \
            s1u[1] = usex ? xw1 : s1u[1]; \
            s1u[2] = usex ? xw2 : s1u[2]; \
            s1u[3] = usex ? xw3 : s1u[3]; \
            S1 = *(const bf16x8*)&s1u; \
            f32x4 c0 = __builtin_amdgcn_mfma_f32_16x16x32_bf16(F00, S0, BB0, 0, 0, 0); \
            MF(F01, S1, c0); \
            { GMATH(c0, hA0); Sb[w0 + (1 - (RP)) * PP] = bf16_cvt(hA0); } \
            if (NT == 2) { \
                f32x4 c1 = __builtin_amdgcn_mfma_f32_16x16x32_bf16(F10, S0, BB1, 0, 0, 0); \
                MF(F11, S1, c1); \
                GMATH(c1, hA1); Sb[w0b + (1 - (RP)) * PP] = bf16_cvt(hA1); \
            } \
        } \
    } else { \
        const bf16x8 S0 = *(const bf16x8*)(Sb + g0 + (RP) * PP); \
        const bf16x8 S1 = *(const bf16x8*)(Sb + g1 + (RP) * PP); \
        const bf16x8 S2 = *(const bf16x8*)(Sb + g2 + (RP) * PP); \
        f32x4 c = __builtin_amdgcn_mfma_f32_16x16x32_bf16(F00, S0, BB0, 0, 0, 0); \
        MF(F01, S1, c); MF(F02, S2, c); \
        if (t > 0) { GMATH(c, hA0); Sb[w1 + (1 - (RP)) * PP] = bf16_cvt(hA0); } \
    } \
    ++t; \
    BAR(); }

    int t = 0;
    #pragma unroll 1
    for (int it = 0; it < 64; ++it) {
        BODY(0, XA)
        BODY(1, XB)
        BODY(0, XC)
        BODY(1, XD)
    }
    BODY(0, XA)   // t = 256: L1 finishes h1[255]; L0 inactive

    // ---- h1[255] straight from registers (10 L1 waves x 4 units = 40) ----
    if (isL1) {
        out[(size_t)(e0 + col) * HID + 4 * TA + qrow] = hA0;
    }
}

extern "C" void kernel_launch(void* const* d_in, const int* in_sizes, int n_in,
                              void* d_out, int out_size, void* d_ws, size_t ws_size,
                              hipStream_t stream) {
    const float* x    = (const float*)d_in[0];
    const float* Wih0 = (const float*)d_in[1];
    const float* Whh0 = (const float*)d_in[2];
    const float* bih0 = (const float*)d_in[3];
    const float* bhh0 = (const float*)d_in[4];
    const float* Wih1 = (const float*)d_in[5];
    const float* Whh1 = (const float*)d_in[6];
    const float* bih1 = (const float*)d_in[7];
    const float* bhh1 = (const float*)d_in[8];
    float* out = (float*)d_out;

    dim3 grid(4096 / EPB), block(NTHR);
    hipLaunchKernelGGL(gru2_kernel, grid, block, 0, stream,
                       x, Wih0, Whh0, bih0, bhh0, Wih1, Whh1, bih1, bhh1, out);
}

// Round 10
// 201.989 us; speedup vs baseline: 1.6551x; 1.1627x over previous
//
#include <hip/hip_runtime.h>

#define T_STEPS 256
#define HID 40
#define EPB 16
#define NTHR 1024          // 16 waves: 0-5 L0 (tiles 2,2,2,2,1,1), 6-15 L1 (1 tile)
#define RR0 72             // L0 row stride (shorts): [h0(40) | x(16) | pad(16)]
#define RR1 56             // L1 row stride (shorts): [h1(40) | pad(16)]
#define P0 (16 * RR0)      // L0 parity stride = 1152 shorts
#define P1 (16 * RR1)      // L1 parity stride = 896 shorts
#define OL1 (2 * P0)       // L1 region offset = 2304 shorts
#define STOT (2 * P0 + 2 * P1)   // 4096 shorts = 8192 B

typedef __attribute__((ext_vector_type(8))) short bf16x8;
typedef __attribute__((ext_vector_type(4))) float f32x4;

__device__ __forceinline__ unsigned short bf16_rne(float v) {
    unsigned int x = __float_as_uint(v);
    unsigned int r = x + 0x7FFFu + ((x >> 16) & 1u);
    return (unsigned short)(r >> 16);
}
__device__ __forceinline__ unsigned short bf16_cvt(float v) {
    unsigned int r;
    asm("v_cvt_pk_bf16_f32 %0, %1, %2" : "=v"(r) : "v"(v), "v"(v));
    return (unsigned short)r;
}
// fast gates (r16-proven): v_exp_f32 = 2^x; v_rcp_f32 replaces IEEE divide
__device__ __forceinline__ float sigm(float v) {
    return __builtin_amdgcn_rcpf(1.0f + __builtin_amdgcn_exp2f(-1.4426950408889634f * v));
}
__device__ __forceinline__ float tanh_f(float v) {
    return 1.0f - 2.0f * __builtin_amdgcn_rcpf(__builtin_amdgcn_exp2f(2.8853900817779268f * v) + 1.0f);
}

#define MF(A_, B_, C_) C_ = __builtin_amdgcn_mfma_f32_16x16x32_bf16(A_, B_, C_, 0, 0, 0)
#define PINV(v) asm volatile("" : "+v"(v))

// r24 = r23 with the CHUNK-1 READ ADDRESS fixed: r23's rd1 = col*RR0 + 32
// dropped the 8*qrow term (R1 had rdl+32 with rdl = col*R0 + 8*qrow), so
// every qrow read h0[32..39] and x never entered L0's MFMA (absmax 0.49).
// Correct: rd1 = rd0 + 32 -> qrow0 h0[32..39], qrow1 x[0..7], qrow2
// x[8..15], qrow3 pad(=0; A-frag zero there).
//
// Structure (r23): R1's 16 waves / 1 barrier / layer skew; [h0|x] L0 row so
// chunk-1 ds_read delivers x with NO reg-splice on the critical path; x
// staged by tid<256 from a 4-deep register ring (1 cvt + 1 b16 ds_write per
// step); single h0 write (L1 reads h0 from L0 region, per-parity addresses
// since P0 != P1); lgkm-only raw barrier (r22-verified safe) so x global
// loads float across barriers.
#define BAR() asm volatile("s_waitcnt lgkmcnt(0)\n\ts_barrier" ::: "memory")

// A-frag over unified K-concat rows [h_self(40) | input(KX)] (r15-proven mapping).
__device__ bf16x8 afrag(const float* Whh, const float* Wih, int KX,
                        int rh, int rx, int c, int qrow) {
    bf16x8 f;
    #pragma unroll
    for (int j = 0; j < 8; ++j) f[j] = 0;
    #pragma unroll
    for (int j = 0; j < 8; ++j) {
        const int k = 32 * c + qrow * 8 + j;
        if (k < 40) {
            if (rh >= 0) f[j] = (short)bf16_rne(Whh[rh * 40 + k]);
        } else if (k < 40 + KX) {
            if (rx >= 0) f[j] = (short)bf16_rne(Wih[rx * KX + (k - 40)]);
        }
    }
    return f;
}

__global__ __launch_bounds__(NTHR, 4)
void gru2_kernel(const float* __restrict__ x,
                 const float* __restrict__ Wih0, const float* __restrict__ Whh0,
                 const float* __restrict__ bih0, const float* __restrict__ bhh0,
                 const float* __restrict__ Wih1, const float* __restrict__ Whh1,
                 const float* __restrict__ bih1, const float* __restrict__ bhh1,
                 float* __restrict__ out)
{
    __shared__ __align__(16) unsigned short S[STOT];

    const int tid  = threadIdx.x;
    const int wid  = tid >> 6;     // 0..15
    const int l    = tid & 63;
    const int col  = l & 15;       // example / MFMA col
    const int qrow = l >> 4;
    const int ps   = (l & 15) & 3; // slot (0=r,1=z,2=nx,3=nh)
    const int pu   = (l & 15) >> 2;
    const int e0   = blockIdx.x * EPB;

    const bool isL1 = wid >= 6;
    const int  NT   = (!isL1 && wid < 4) ? 2 : 1;
    const int  TA   = isL1 ? (wid - 6) : (wid < 4 ? 2 * wid : wid + 4);
    const int  TB   = (NT == 2) ? TA + 1 : TA;
    const bool dB   = (NT != 2);

    const float* Whh = isL1 ? Whh1 : Whh0;
    const float* Wih = isL1 ? Wih1 : Wih0;
    const float* bih = isL1 ? bih1 : bih0;
    const float* bhh = isL1 ? bhh1 : bhh0;
    const int KX = isL1 ? 40 : 16;

    // ---- A-frags + biases ----
    bf16x8 ZF;
    #pragma unroll
    for (int j = 0; j < 8; ++j) ZF[j] = 0;
    bf16x8 F00=ZF,F01=ZF,F02=ZF, F10=ZF,F11=ZF;
    f32x4 BB0, BB1;
    {
#define RRX(u, RH, RX) \
        const int RH = (ps == 2) ? -1 : (ps == 0 ? (u) : ps == 1 ? 40 + (u) : 80 + (u)); \
        const int RX = (ps == 3) ? -1 : (ps == 0 ? (u) : ps == 1 ? 40 + (u) : 80 + (u));
        {
            const int u0 = 4 * TA + pu;
            RRX(u0, rh0, rx0);
            F00 = afrag(Whh, Wih, KX, rh0, rx0, 0, qrow);
            F01 = afrag(Whh, Wih, KX, rh0, rx0, 1, qrow);
            if (isL1) F02 = afrag(Whh, Wih, KX, rh0, rx0, 2, qrow);
        }
        if (NT == 2) {
            const int u1 = 4 * TB + pu;
            RRX(u1, rh1, rx1);
            F10 = afrag(Whh, Wih, KX, rh1, rx1, 0, qrow);
            F11 = afrag(Whh, Wih, KX, rh1, rx1, 1, qrow);
        }
        const int uc0 = 4 * TA + qrow;
        const int uc1 = 4 * TB + qrow;
        BB0[0] = bih[uc0] + bhh[uc0];
        BB0[1] = bih[40 + uc0] + bhh[40 + uc0];
        BB0[2] = bih[80 + uc0];
        BB0[3] = bhh[80 + uc0];
        BB1[0] = dB ? 0.f : (bih[uc1] + bhh[uc1]);
        BB1[1] = dB ? 0.f : (bih[40 + uc1] + bhh[40 + uc1]);
        BB1[2] = dB ? 0.f : bih[80 + uc1];
        BB1[3] = dB ? 0.f : bhh[80 + uc1];
    }
    PINV(F00); PINV(F01); PINV(F02);
    PINV(F10); PINV(F11);
    PINV(BB0); PINV(BB1);

    // ---- per-lane LDS addresses (shorts; parity selected at compile time) ----
    // L0 row [h0(40)|x(16)|pad(16)]: chunk0 at 8q..8q+7; chunk1 at
    // 32+8q..39+8q: qrow0 h0[32..39], qrow1 x[0..7], qrow2 x[8..15], qrow3 pad=0.
    const int rd0 = col * RR0 + 8 * qrow;
    const int rd1 = rd0 + 32;
    // L1 concat [h1(40) | h0(40)]: group g = 4c + qrow; h1 in own region
    // (stride P1), h0 in L0 region (stride P0) -> precompute both parities.
    int g0p0, g0p1, g1p0, g1p1, g2p0, g2p1;
    {
        auto ga = [&](int g, int p) -> int {
            if (g < 5)  return OL1 + p * P1 + col * RR1 + 8 * g;      // h1
            if (g < 10) return p * P0 + col * RR0 + 8 * (g - 5);      // h0
            return p * P0 + col * RR0;                                // dead (A=0)
        };
        g0p0 = ga(qrow, 0);     g0p1 = ga(qrow, 1);
        g1p0 = ga(4 + qrow, 0); g1p1 = ga(4 + qrow, 1);
        g2p0 = ga(8 + qrow, 0); g2p1 = ga(8 + qrow, 1);
    }
    // write offsets (parity (1-RP) applied as compile-time immediate)
    const int w0  = col * RR0 + 4 * TA + qrow;         // L0 tile A unit
    const int w0b = col * RR0 + 4 * TB + qrow;         // L0 tile B unit
    const int w1  = OL1 + col * RR1 + 4 * TA + qrow;   // L1 unit
    unsigned short* Sb = &S[0];
    float hA0 = 0.f, hA1 = 0.f;

    // ---- x staging lanes: tid<256, one (example, feature) scalar each ----
    const bool xth = tid < 256;
    const int xe = tid >> 4, xk = tid & 15;
    const int xsl = xe * RR0 + 40 + xk;                // + parity at use
    const float* xrow = x + (size_t)(e0 + xe) * (T_STEPS * 16) + xk;

    // ---- zero LDS (initial h = 0; pads must stay 0) ----
    for (int idx = tid; idx < STOT; idx += NTHR) Sb[idx] = 0;
    __syncthreads();
    // x[0] into parity 0; ring holds x[1..4]
    float XA = 0.f, XB = 0.f, XC = 0.f, XD = 0.f;
    if (xth) {
        Sb[xsl] = bf16_cvt(xrow[0]);
        XA = xrow[16];       // x[1]
        XB = xrow[32];       // x[2]
        XC = xrow[48];       // x[3]
        XD = xrow[64];       // x[4]
    }
    __syncthreads();

#define GMATH(C, H) \
    const float r_ = sigm(C[0]); \
    const float z_ = sigm(C[1]); \
    const float n_ = tanh_f(C[2] + r_ * C[3]); \
    H = n_ + z_ * (H - n_);

    // BODY(RP, XQ): step t. XQ holds x[t+1]; write it to parity (1-RP) for
    // step t+1, then refill XQ with x[t+5] (used again at step t+4).
#define BODY(RP, XQ) { \
    if (!isL1) { \
        if (xth && t < T_STEPS - 1) { \
            Sb[xsl + (1 - (RP)) * P0] = bf16_cvt(XQ); \
            if (t + 5 < T_STEPS) XQ = xrow[(t + 5) * 16]; \
        } \
        if (t < T_STEPS) { \
            const bf16x8 S0 = *(const bf16x8*)(Sb + rd0 + (RP) * P0); \
            const bf16x8 S1 = *(const bf16x8*)(Sb + rd1 + (RP) * P0); \
            f32x4 c0 = __builtin_amdgcn_mfma_f32_16x16x32_bf16(F00, S0, BB0, 0, 0, 0); \
            MF(F01, S1, c0); \
            { GMATH(c0, hA0); Sb[w0 + (1 - (RP)) * P0] = bf16_cvt(hA0); } \
            if (NT == 2) { \
                f32x4 c1 = __builtin_amdgcn_mfma_f32_16x16x32_bf16(F10, S0, BB1, 0, 0, 0); \
                MF(F11, S1, c1); \
                GMATH(c1, hA1); Sb[w0b + (1 - (RP)) * P0] = bf16_cvt(hA1); \
            } \
        } \
    } else { \
        const bf16x8 S0 = *(const bf16x8*)(Sb + ((RP) ? g0p1 : g0p0)); \
        const bf16x8 S1 = *(const bf16x8*)(Sb + ((RP) ? g1p1 : g1p0)); \
        const bf16x8 S2 = *(const bf16x8*)(Sb + ((RP) ? g2p1 : g2p0)); \
        f32x4 c = __builtin_amdgcn_mfma_f32_16x16x32_bf16(F00, S0, BB0, 0, 0, 0); \
        MF(F01, S1, c); MF(F02, S2, c); \
        if (t > 0) { GMATH(c, hA0); Sb[w1 + (1 - (RP)) * P1] = bf16_cvt(hA0); } \
    } \
    ++t; \
    BAR(); }

    int t = 0;
    #pragma unroll 1
    for (int it = 0; it < 64; ++it) {
        BODY(0, XA)
        BODY(1, XB)
        BODY(0, XC)
        BODY(1, XD)
    }
    BODY(0, XA)   // t = 256: L1 finishes h1[255]; L0 inactive

    // ---- h1[255] straight from registers (10 L1 waves x 4 units = 40) ----
    if (isL1) {
        out[(size_t)(e0 + col) * HID + 4 * TA + qrow] = hA0;
    }
}

extern "C" void kernel_launch(void* const* d_in, const int* in_sizes, int n_in,
                              void* d_out, int out_size, void* d_ws, size_t ws_size,
                              hipStream_t stream) {
    const float* x    = (const float*)d_in[0];
    const float* Wih0 = (const float*)d_in[1];
    const float* Whh0 = (const float*)d_in[2];
    const float* bih0 = (const float*)d_in[3];
    const float* bhh0 = (const float*)d_in[4];
    const float* Wih1 = (const float*)d_in[5];
    const float* Whh1 = (const float*)d_in[6];
    const float* bih1 = (const float*)d_in[7];
    const float* bhh1 = (const float*)d_in[8];
    float* out = (float*)d_out;

    dim3 grid(4096 / EPB), block(NTHR);
    hipLaunchKernelGGL(gru2_kernel, grid, block, 0, stream,
                       x, Wih0, Whh0, bih0, bhh0, Wih1, Whh1, bih1, bhh1, out);
}